// Round 1
// baseline (484.553 us; speedup 1.0000x reference)
//
#include <hip/hip_runtime.h>

#define NN 50000
#define NE 800000
#define D 64

// a = x @ W1[:64] + b1 ; b = x @ W1[64:]   (both [N,64] f32)
// one wave per node, lane = output feature
__global__ void prep_ab(const float* __restrict__ x,
                        const float* __restrict__ W1,
                        const float* __restrict__ b1,
                        float* __restrict__ a,
                        float* __restrict__ b) {
    int node = (blockIdx.x * blockDim.x + threadIdx.x) >> 6;
    int lane = threadIdx.x & 63;
    if (node >= NN) return;
    float xv = x[node * D + lane];
    float acca = 0.f, accb = 0.f;
#pragma unroll 8
    for (int k = 0; k < D; ++k) {
        float xk = __shfl(xv, k, 64);
        acca = fmaf(xk, W1[k * D + lane], acca);
        accb = fmaf(xk, W1[(D + k) * D + lane], accb);
    }
    a[node * D + lane] = acca + b1[lane];
    b[node * D + lane] = accb;
}

// per (edge, feature): h = relu(a[dst] + b[src]); hsum[dst] += h; deg[dst] += 1
__global__ void edge_scatter(const int* __restrict__ ei,
                             const float* __restrict__ a,
                             const float* __restrict__ b,
                             float* __restrict__ hsum,
                             float* __restrict__ deg) {
    int gid = blockIdx.x * blockDim.x + threadIdx.x;
    int e = gid >> 6;
    int f = gid & 63;
    if (e >= NE) return;
    int src = ei[e];            // row 0: src
    int dst = ei[NE + e];       // row 1: dst
    float h = a[dst * D + f] + b[src * D + f];
    h = fmaxf(h, 0.f);
    atomicAdd(&hsum[dst * D + f], h);
    if (f == 0) atomicAdd(&deg[dst], 1.0f);
}

// per node: aggr = hsum@W2 + deg*b2 ; u = relu(x@U1[:64] + aggr@U1[64:] + ub1)
//           out = u@U2 + ub2
__global__ void node_update(const float* __restrict__ x,
                            const float* __restrict__ hsum,
                            const float* __restrict__ deg,
                            const float* __restrict__ W2,
                            const float* __restrict__ b2,
                            const float* __restrict__ U1,
                            const float* __restrict__ ub1,
                            const float* __restrict__ U2,
                            const float* __restrict__ ub2,
                            float* __restrict__ out) {
    int node = (blockIdx.x * blockDim.x + threadIdx.x) >> 6;
    int lane = threadIdx.x & 63;
    if (node >= NN) return;
    float hs = hsum[node * D + lane];
    float xv = x[node * D + lane];
    float dg = deg[node];

    float aggr = dg * b2[lane];
#pragma unroll 8
    for (int k = 0; k < D; ++k)
        aggr = fmaf(__shfl(hs, k, 64), W2[k * D + lane], aggr);

    float t = ub1[lane];
#pragma unroll 8
    for (int k = 0; k < D; ++k) {
        t = fmaf(__shfl(xv, k, 64), U1[k * D + lane], t);
        t = fmaf(__shfl(aggr, k, 64), U1[(D + k) * D + lane], t);
    }
    t = fmaxf(t, 0.f);

    float o = ub2[lane];
#pragma unroll 8
    for (int k = 0; k < D; ++k)
        o = fmaf(__shfl(t, k, 64), U2[k * D + lane], o);

    out[node * D + lane] = o;
}

extern "C" void kernel_launch(void* const* d_in, const int* in_sizes, int n_in,
                              void* d_out, int out_size, void* d_ws, size_t ws_size,
                              hipStream_t stream) {
    const float* x   = (const float*)d_in[0];
    const int*   ei  = (const int*)d_in[1];
    const float* W1  = (const float*)d_in[2];
    const float* b1  = (const float*)d_in[3];
    const float* W2  = (const float*)d_in[4];
    const float* b2  = (const float*)d_in[5];
    const float* U1  = (const float*)d_in[6];
    const float* ub1 = (const float*)d_in[7];
    const float* U2  = (const float*)d_in[8];
    const float* ub2 = (const float*)d_in[9];
    float* out = (float*)d_out;

    float* a    = (float*)d_ws;            // [NN*D]
    float* b    = a + (size_t)NN * D;      // [NN*D]
    float* hsum = b + (size_t)NN * D;      // [NN*D]
    float* deg  = hsum + (size_t)NN * D;   // [NN]

    // hsum and deg must start at zero every launch (ws is poisoned 0xAA)
    hipMemsetAsync(hsum, 0, ((size_t)NN * D + NN) * sizeof(float), stream);

    prep_ab<<<(NN + 3) / 4, 256, 0, stream>>>(x, W1, b1, a, b);

    int nthreads = NE * D; // 51.2M
    edge_scatter<<<(nthreads + 255) / 256, 256, 0, stream>>>(ei, a, b, hsum, deg);

    node_update<<<(NN + 3) / 4, 256, 0, stream>>>(x, hsum, deg, W2, b2,
                                                  U1, ub1, U2, ub2, out);
}